// Round 8
// baseline (243.155 us; speedup 1.0000x reference)
//
#include <hip/hip_runtime.h>

typedef __bf16 bf16x8 __attribute__((ext_vector_type(8)));
typedef float f32x4 __attribute__((ext_vector_type(4)));

__device__ __forceinline__ unsigned short f2bf(float f) {
    union { float f; unsigned int u; } v; v.f = f;
    unsigned int u = v.u;
    unsigned int r = (u + 0x7fffu + ((u >> 16) & 1u)) >> 16;
    return (unsigned short)r;
}

// ---------------------------------------------------------------------------
// Kernel 1: reconstruct TT conv weights -> bf16, MFMA-fragment layout.
// kidx = (kh*3+kw)*128 + c ; stored wb[(kidx>>3)*2048 + d*8 + (kidx&7)]
// (lane&15 = d, lane>>4 = k-granule — valid as either A or B operand.)
// ---------------------------------------------------------------------------
__global__ void build_w_kernel(const float* __restrict__ core0,
                               const float* __restrict__ core1,
                               const float* __restrict__ core2,
                               unsigned short* __restrict__ wb) {
    __shared__ float s1[96];   // core1[d]: [r][kh][s]
    __shared__ float s2[12];   // core2[d]: [s][kw]
    const int d = blockIdx.x;
    const int c = threadIdx.x;   // 128 threads
    if (c < 96) s1[c] = core1[d * 96 + c];
    if (c >= 96 && c < 108) s2[c - 96] = core2[d * 12 + (c - 96)];
    __syncthreads();
    float t0[8];
#pragma unroll
    for (int r = 0; r < 8; ++r) t0[r] = core0[(d * 128 + c) * 8 + r];
#pragma unroll
    for (int kh = 0; kh < 3; ++kh) {
        float v[4] = {0.f, 0.f, 0.f, 0.f};
#pragma unroll
        for (int r = 0; r < 8; ++r)
#pragma unroll
            for (int s = 0; s < 4; ++s)
                v[s] += t0[r] * s1[(r * 3 + kh) * 4 + s];
#pragma unroll
        for (int kw = 0; kw < 3; ++kw) {
            float val = 0.f;
#pragma unroll
            for (int s = 0; s < 4; ++s) val += v[s] * s2[s * 3 + kw];
            const int kidx = (kh * 3 + kw) * 128 + c;
            wb[(kidx >> 3) * 2048 + d * 8 + (kidx & 7)] = f2bf(val);
        }
    }
}

// ---------------------------------------------------------------------------
// Kernel 2: implicit-GEMM conv, 512 threads / 8 waves, wave-row-split.
// Block (n, h-pair): out[n, 0:256, h0..h0+1, 0:64]. Waves 0-3 row h0,
// waves 4-7 row h0+1; per-wave tile 64d x 64w, acc[4][4] in AGPRs.
// Round-7 changes vs round-6 (which was NEUTRAL vs round-4 — K-loop is
// NOT latency-bound; compiler already schedules ds_read/MFMA):
//  (1) OPERAND SWAP: mfma(A=x_frag, B=w_frag) -> D rows = w, cols = d.
//      Same register data (A/B frag layouts are symmetric), but each acc
//      f32x4 now spans 4 consecutive w -> epilogue is 16 aligned
//      global_store_dwordx4 instead of 64 scalar stores (all full-line).
//  (2) T5: s_setprio(1) around each MFMA cluster — co-resident blocks are
//      at different phases (stage vs K-loop vs epilogue); priority keeps
//      the matrix pipe fed while other waves issue memory ops.
// Register budget: 60 VGPR + 64 AGPR = 124 -> 4 waves/SIMD (16 waves/CU),
// the hard occupancy cap; any acc growth spills (rounds 1-2 lesson).
// ---------------------------------------------------------------------------
#define LC 136   // padded c dim: byte stride 272 => 16B-granule stride 17 ≡ 1 (mod 8)

__global__ __launch_bounds__(512, 2) void conv_mfma_kernel(
    const float* __restrict__ x, const unsigned short* __restrict__ wb,
    const float* __restrict__ bias, float* __restrict__ out) {
    __shared__ __align__(16) unsigned short xl[4 * 66 * LC];   // 71,808 B

    const int tid  = threadIdx.x;
    const int lane = tid & 63;
    const int wv   = tid >> 6;          // 0..7
    const int l15  = lane & 15;
    const int quad = lane >> 4;
    const int bid  = blockIdx.x;
    const int n    = bid >> 5;          // 32 n
    const int h0   = (bid & 31) << 1;   // 32 h-pairs
    const int rowsel = wv >> 2;         // 0: row h0, 1: row h0+1

    // ---- zero halo columns (wcol 0 and 65) of all 4 slots ----
    if (tid < 128) {
        const int s   = tid >> 5;
        const int j   = tid & 31;
        const int col = (j >> 4) ? 65 : 0;
        const int c   = (j & 15) << 3;
        *(uint4*)(xl + (s * 66 + col) * LC + c) = make_uint4(0u, 0u, 0u, 0u);
    }

    // ---- stage image rows h0-1..h0+2 as bf16 [slot][wcol][c]; OOB -> zeros ----
#pragma unroll 2
    for (int i = 0; i < 4; ++i) {
        const int it  = tid + (i << 9);
        const int w4  = it & 15;
        const int cg  = (it >> 4) & 31;
        const int row = it >> 9;           // 0..3
        const int rimg = h0 + row - 1;
        float4 p0 = make_float4(0.f, 0.f, 0.f, 0.f), p1 = p0, p2 = p0, p3 = p0;
        const int c = cg << 2;
        const int w = w4 << 2;
        if (rimg >= 0 && rimg < 64) {
            const float4* gp = (const float4*)(x + (((n * 128 + c) * 64 + rimg) * 64 + w));
            p0 = gp[0];
            p1 = gp[1024];   // +1 c-plane (64*64 floats)
            p2 = gp[2048];
            p3 = gp[3072];
        }
        unsigned short* base = xl + (row * 66 + w + 1) * LC + c;
        *(ushort4*)(base)          = make_ushort4(f2bf(p0.x), f2bf(p1.x), f2bf(p2.x), f2bf(p3.x));
        *(ushort4*)(base + LC)     = make_ushort4(f2bf(p0.y), f2bf(p1.y), f2bf(p2.y), f2bf(p3.y));
        *(ushort4*)(base + 2 * LC) = make_ushort4(f2bf(p0.z), f2bf(p1.z), f2bf(p2.z), f2bf(p3.z));
        *(ushort4*)(base + 3 * LC) = make_ushort4(f2bf(p0.w), f2bf(p1.w), f2bf(p2.w), f2bf(p3.w));
    }

    f32x4 acc[4][4];
#pragma unroll
    for (int a0 = 0; a0 < 4; ++a0)
#pragma unroll
        for (int b0 = 0; b0 < 4; ++b0) acc[a0][b0] = (f32x4){0.f, 0.f, 0.f, 0.f};

    const int dwave = (wv & 3) << 6;                 // 64 d per wave
    const bf16x8* wgv = (const bf16x8*)wb;           // 16 B granules
    const int abase = quad * 256 + dwave + l15;      // lane's frag index within a chunk

    // weight-frag double buffer: prefetch chunk 0 before the barrier
    bf16x8 abuf[2][4];
#pragma unroll
    for (int dt = 0; dt < 4; ++dt) abuf[0][dt] = wgv[abase + dt * 16];

    __syncthreads();   // the ONLY barrier

    // x-frag base: rowsel picks the wave's image-row window (slots rowsel..rowsel+2)
    const unsigned short* bb = xl + (rowsel * 66 + l15) * LC + quad * 8;

    // x-frag double buffer: load chunk 0's 4 frags
    bf16x8 bbuf[2][4];
#pragma unroll
    for (int pt = 0; pt < 4; ++pt) {
        bbuf[0][pt] = *(const bf16x8*)(bb + pt * 16 * LC);
    }

#pragma unroll
    for (int ch = 0; ch < 36; ++ch) {
        const int cur = ch & 1;
        const int nxt = cur ^ 1;
        const bool more = (ch + 1) < 36;
        const int ntap = (ch + 1) >> 2;
        const int nc4  = (ch + 1) & 3;
        const int nkh  = ntap / 3;
        const int nkw  = ntap - nkh * 3;
        const unsigned short* nbp = bb + (nkh * 66 + nkw) * LC + (nc4 << 5);

        // ---- group 0: A = x-frag (rows=w), B = w-frag (cols=d) ----
        __builtin_amdgcn_s_setprio(1);
#pragma unroll
        for (int dt = 0; dt < 4; ++dt)
            acc[dt][0] = __builtin_amdgcn_mfma_f32_16x16x32_bf16(
                bbuf[cur][0], abuf[cur][dt], acc[dt][0], 0, 0, 0);
        __builtin_amdgcn_s_setprio(0);
        if (more) {   // weight prefetch for chunk ch+1
            const bf16x8* g2 = wgv + (ch + 1) * 1024 + abase;
#pragma unroll
            for (int dt = 0; dt < 4; ++dt) abuf[nxt][dt] = g2[dt * 16];
        }
        // ---- group 1 ----
        __builtin_amdgcn_s_setprio(1);
#pragma unroll
        for (int dt = 0; dt < 4; ++dt)
            acc[dt][1] = __builtin_amdgcn_mfma_f32_16x16x32_bf16(
                bbuf[cur][1], abuf[cur][dt], acc[dt][1], 0, 0, 0);
        __builtin_amdgcn_s_setprio(0);
        if (more) bbuf[nxt][0] = *(const bf16x8*)(nbp);
        // ---- group 2 ----
        __builtin_amdgcn_s_setprio(1);
#pragma unroll
        for (int dt = 0; dt < 4; ++dt)
            acc[dt][2] = __builtin_amdgcn_mfma_f32_16x16x32_bf16(
                bbuf[cur][2], abuf[cur][dt], acc[dt][2], 0, 0, 0);
        __builtin_amdgcn_s_setprio(0);
        if (more) bbuf[nxt][1] = *(const bf16x8*)(nbp + 16 * LC);
        // ---- group 3 ----
        __builtin_amdgcn_s_setprio(1);
#pragma unroll
        for (int dt = 0; dt < 4; ++dt)
            acc[dt][3] = __builtin_amdgcn_mfma_f32_16x16x32_bf16(
                bbuf[cur][3], abuf[cur][dt], acc[dt][3], 0, 0, 0);
        __builtin_amdgcn_s_setprio(0);
        if (more) {
            bbuf[nxt][2] = *(const bf16x8*)(nbp + 32 * LC);
            bbuf[nxt][3] = *(const bf16x8*)(nbp + 48 * LC);
        }
    }

    // ---- epilogue: bias + vectorized store. D: col(d)=l15, row(w)=quad*4+rr ----
    const float bv = bias[0];
    const int oh = h0 + rowsel;
#pragma unroll
    for (int dt = 0; dt < 4; ++dt) {
        const int d = dwave + dt * 16 + l15;
        float* orow = out + ((n * 256 + d) * 64 + oh) * 64;
#pragma unroll
        for (int pt = 0; pt < 4; ++pt) {
            const int w = pt * 16 + (quad << 2);
            f32x4 v = acc[dt][pt];
            v[0] += bv; v[1] += bv; v[2] += bv; v[3] += bv;
            *(f32x4*)(orow + w) = v;   // one global_store_dwordx4, 16B aligned
        }
    }
}

extern "C" void kernel_launch(void* const* d_in, const int* in_sizes, int n_in,
                              void* d_out, int out_size, void* d_ws, size_t ws_size,
                              hipStream_t stream) {
    const float* x     = (const float*)d_in[0];
    const float* core0 = (const float*)d_in[1];
    const float* core1 = (const float*)d_in[2];
    const float* core2 = (const float*)d_in[3];
    const float* bias  = (const float*)d_in[4];
    unsigned short* wb = (unsigned short*)d_ws;   // 1152*256*2 = 589,824 B

    build_w_kernel<<<256, 128, 0, stream>>>(core0, core1, core2, wb);
    conv_mfma_kernel<<<1024, 512, 0, stream>>>(x, wb, bias, (float*)d_out);
}